// Round 5
// baseline (460.661 us; speedup 1.0000x reference)
//
#include <hip/hip_runtime.h>

#define NSHOTS 4
#define NT     512
#define NZ     256
#define NX     256
#define NRECS  128

static constexpr float DTf    = 0.001f;
static constexpr float INVDH2 = 1.0f / (10.0f * 10.0f);

#define KS     16                 // steps per global phase
#define KIN    4                  // steps between intra-WG exchanges
#define TILE   32                 // interior tile edge
#define EXT    64                 // WG ext z rows (TILE + 2*KS)
#define SLAB   8                  // exact rows per wave
#define WROWS  16                 // register window rows per wave (SLAB + 2*KIN)
#define WPAIR  8                  // WROWS/2 v2f pairs
#define NWAVES 8
#define BLOCK  512
#define NWG    (NSHOTS * 64)      // 256 WGs, one per CU
#define NPHASE (NT / KS)          // 32
#define LSTRIDE 32                // dwords between flags (128 B)

typedef float v2f __attribute__((ext_vector_type(2)));

// lane i <- lane i-1 (left x-neighbor); OOB lane 0 reads 0 (bound_ctrl=1)
__device__ __forceinline__ float nbr_left(float v) {
  return __int_as_float(__builtin_amdgcn_update_dpp(
      0, __float_as_int(v), 0x138 /*WAVE_SHR1*/, 0xf, 0xf, true));
}
// lane i <- lane i+1 (right x-neighbor); OOB lane 63 reads 0
__device__ __forceinline__ float nbr_right(float v) {
  return __int_as_float(__builtin_amdgcn_update_dpp(
      0, __float_as_int(v), 0x130 /*WAVE_SHL1*/, 0xf, 0xf, true));
}

// LLC-coherent (cross-XCD) access: agent-scope relaxed -> sc0 sc1.
__device__ __forceinline__ float2 gload2(const float2* p) {
  unsigned long long u = __hip_atomic_load((const unsigned long long*)p,
      __ATOMIC_RELAXED, __HIP_MEMORY_SCOPE_AGENT);
  return make_float2(__uint_as_float((unsigned)u),
                     __uint_as_float((unsigned)(u >> 32)));
}
__device__ __forceinline__ void gstore2(float2* p, float a, float b) {
  unsigned long long u = ((unsigned long long)__float_as_uint(b) << 32) |
                         (unsigned long long)__float_as_uint(a);
  __hip_atomic_store((unsigned long long*)p, u,
      __ATOMIC_RELAXED, __HIP_MEMORY_SCOPE_AGENT);
}
__device__ __forceinline__ unsigned fload(const unsigned* p) {
  return __hip_atomic_load(p, __ATOMIC_RELAXED, __HIP_MEMORY_SCOPE_AGENT);
}
__device__ __forceinline__ void fstore(unsigned* p, unsigned v) {
  __hip_atomic_store(p, v, __ATOMIC_RELAXED, __HIP_MEMORY_SCOPE_AGENT);
}

__global__ __launch_bounds__(BLOCK, 2) void wave_pk(
    float2* __restrict__ g0, float2* __restrict__ g1,   // interleaved (cur,prev)
    const float* __restrict__ vp, const float* __restrict__ xwav,
    const int* __restrict__ src_z, const int* __restrict__ src_x,
    const int* __restrict__ rec_z, const int* __restrict__ rec_x,
    float* __restrict__ out,                            // [NSHOTS*NT*NRECS]
    unsigned* __restrict__ bar)                         // wFlag[NWG] @128B
{
  const int bid  = blockIdx.x;
  const int s    = bid >> 6;
  const int tz   = (bid >> 3) & 7;
  const int tx   = bid & 7;
  const int tid  = threadIdx.x;
  const int w    = tid >> 6;
  const int lane = tid & 63;

  const int gz0 = tz * TILE - KS;       // WG ext origin (z)
  const int gx0 = tx * TILE - KS;       // WG ext origin (x)
  const int gx  = gx0 + lane;
  const int wz0 = w * SLAB - KIN;       // my window's ext-row base (can be -4)
  const bool xok = (unsigned)gx < (unsigned)NX;

  __shared__ float2 xch[EXT][64];       // slab exchange buffer (cur,prev)

  // per-window-row validity: inside WG-ext AND inside domain AND x in domain
  unsigned okBits = 0;
  #pragma unroll
  for (int i = 0; i < WROWS; ++i) {
    const int e = wz0 + i;
    if ((unsigned)e < (unsigned)EXT &&
        (unsigned)(gz0 + e) < (unsigned)NZ && xok) okBits |= 1u << i;
  }
  const int offBase = (s * NZ + gz0 + wz0) * NX + gx;   // row i -> offBase+i*NX

  // coefficients; invalid rows get c2=0 -> stay exactly 0 (zero-pad semantics)
  v2f c22[WPAIR], d22[WPAIR], a2[WPAIR], b2[WPAIR];
  #pragma unroll
  for (int p = 0; p < WPAIR; ++p) {
    #pragma unroll
    for (int h = 0; h < 2; ++h) {
      const int i = 2 * p + h;
      float v = ((okBits >> i) & 1) ? vp[(gz0 + wz0 + i) * NX + gx] : 0.0f;
      v *= DTf;
      const float c2 = v * v * INVDH2;
      if (h == 0) { c22[p].x = c2; d22[p].x = 2.0f - 4.0f * c2; }
      else        { c22[p].y = c2; d22[p].y = 2.0f - 4.0f * c2; }
    }
    a2[p] = (v2f)(0.0f); b2[p] = (v2f)(0.0f);
  }

  // writeback/owner threads: slab is WG-interior (waves 2..5), interior lane
  const bool wbT = (w >= 2 && w < 6) && (lane >= KS && lane < KS + TILE);

  // receiver ownership (owner thread is always a wbT thread):
  // 2 packed fast slots + overflow bitmask
  unsigned e0 = 0, e1 = 0, rB0 = 0, rB1 = 0, rB2 = 0, rB3 = 0;
  {
    const int iz0 = tz * TILE, ix0 = tx * TILE;
    int cnt = 0;
    if (wbT) {
      #pragma unroll 1
      for (int r = 0; r < NRECS; ++r) {
        const int er = rec_z[s * NRECS + r] - iz0;   // 0..31 if in tile
        const int ex = rec_x[s * NRECS + r] - ix0;
        if ((unsigned)er < (unsigned)TILE && (unsigned)ex < (unsigned)TILE) {
          const int ew = (er + KS) >> 3;             // owning wave
          if (ew == w && ex + KS == lane) {
            const unsigned e = 0x8000u | ((unsigned)((er + KS) & 7) << 8) |
                               (unsigned)r;
            if (cnt == 0) e0 = e;
            else if (cnt == 1) e1 = e;
            else {
              if (r < 32)      rB0 |= 1u << r;
              else if (r < 64) rB1 |= 1u << (r - 32);
              else if (r < 96) rB2 |= 1u << (r - 64);
              else             rB3 |= 1u << (r - 96);
            }
            ++cnt;
          }
        }
      }
    }
  }
  const bool hasOvf = (rB0 | rB1 | rB2 | rB3) != 0;
  const int iz0g = tz * TILE;

  // source: ext coords; must lie inside WG-ext AND my window to inject
  const int slz = src_z[s] - gz0;
  const int slx = src_x[s] - gx0;
  const int srcRow = slz - wz0;                        // window row
  const bool hasSrc = ((unsigned)slz < (unsigned)EXT) &&
                      ((unsigned)slx < 64u) &&
                      ((unsigned)srcRow < (unsigned)WROWS);
  const bool srcLane = (slx == lane);

  // neighbor flag index (wave-0 lanes 0..7 poll the 8 surrounding tiles)
  int nb = -1;
  if (tid < 8) {
    const int k  = (tid < 4) ? tid : tid + 1;          // skip center of 3x3
    const int dz = k / 3 - 1, dx = k % 3 - 1;
    const int qz = tz + dz, qx = tx + dx;
    if ((unsigned)qz < 8u && (unsigned)qx < 8u)
      nb = (s << 6) | (qz << 3) | qx;
  }
  unsigned* wF = bar;

  float amp[KS];

  // value of slab row srow (0..7) from nxt (pairs 2..5)
  auto selSlab = [&](const v2f (&n)[WPAIR], int srow) -> float {
    const v2f pA = (srow & 2) ? n[3] : n[2];
    const v2f pB = (srow & 2) ? n[5] : n[4];
    const v2f pp = (srow & 4) ? pB : pA;
    return (srow & 1) ? pp.y : pp.x;
  };

  // one step: pure registers + DPP (no LDS, no barrier)
  auto do_step = [&](v2f (&cur)[WPAIR], v2f (&nxt)[WPAIR], int tau, int t0) {
    #pragma unroll
    for (int p = 0; p < WPAIR; ++p) {
      const float cx = cur[p].x, cy = cur[p].y;
      const float upx = (p == 0)         ? 0.0f : cur[p - 1].y;
      const float dny = (p == WPAIR - 1) ? 0.0f : cur[p + 1].x;
      v2f ud, lr;
      ud.x = upx + cy;
      ud.y = cx + dny;
      lr.x = nbr_left(cx) + nbr_right(cx);
      lr.y = nbr_left(cy) + nbr_right(cy);
      const v2f sum = ud + lr;
      v2f t = __builtin_elementwise_fma(c22[p], sum, -nxt[p]);
      t = __builtin_elementwise_fma(d22[p], cur[p], t);
      nxt[p] = t;
    }
    if (hasSrc) {                       // wave-uniform; ~7/256 WGs pay
      const float av = amp[tau];
      #pragma unroll
      for (int p = 0; p < WPAIR; ++p) {
        nxt[p].x += (srcLane && srcRow == 2 * p)     ? av : 0.0f;
        nxt[p].y += (srcLane && srcRow == 2 * p + 1) ? av : 0.0f;
      }
    }
    const int t = t0 + tau;
    if (e0 & 0x8000u)
      out[(s * NT + t) * NRECS + (e0 & 127u)] = selSlab(nxt, (e0 >> 8) & 7);
    if (e1 & 0x8000u)
      out[(s * NT + t) * NRECS + (e1 & 127u)] = selSlab(nxt, (e1 >> 8) & 7);
    if (hasOvf) {
      #pragma unroll
      for (int wd = 0; wd < 4; ++wd) {
        unsigned m = (wd == 0) ? rB0 : (wd == 1) ? rB1 : (wd == 2) ? rB2 : rB3;
        while (m) {
          const int b = __builtin_ctz(m); m &= m - 1;
          const int r = wd * 32 + b;
          const int srow = (rec_z[s * NRECS + r] - iz0g + KS) & 7;
          out[(s * NT + t) * NRECS + r] = selSlab(nxt, srow);
        }
      }
    }
  };

  // intra-WG slab->halo exchange through LDS (every KIN steps)
  auto exchange = [&]() {
    const int eb = w * SLAB;
    #pragma unroll
    for (int k = 0; k < SLAB; ++k) {    // publish slab (pairs 2..5)
      const int pr = 2 + (k >> 1);
      xch[eb + k][lane] = (k & 1) ? make_float2(a2[pr].y, b2[pr].y)
                                  : make_float2(a2[pr].x, b2[pr].x);
    }
    __syncthreads();
    if (w > 0) {
      #pragma unroll
      for (int i = 0; i < KIN; ++i) {   // halo-above -> pairs 0,1
        const float2 f = xch[wz0 + i][lane];
        if (i & 1) { a2[i >> 1].y = f.x; b2[i >> 1].y = f.y; }
        else       { a2[i >> 1].x = f.x; b2[i >> 1].x = f.y; }
      }
    }
    if (w < NWAVES - 1) {
      #pragma unroll
      for (int i = WROWS - KIN; i < WROWS; ++i) {  // halo-below -> pairs 6,7
        const float2 f = xch[wz0 + i][lane];
        if (i & 1) { a2[i >> 1].y = f.x; b2[i >> 1].y = f.y; }
        else       { a2[i >> 1].x = f.x; b2[i >> 1].x = f.y; }
      }
    }
    __syncthreads();                    // WAR: reads done before next publish
  };

  #pragma unroll 1
  for (int ph = 0; ph < NPHASE; ++ph) {
    const int t0 = ph * KS;

    {   // 16 source amps (independent of flags -> before poll)
      const float4* xw4 = (const float4*)(xwav + s * NT + t0);
      #pragma unroll
      for (int q = 0; q < KS / 4; ++q) {
        const float4 v = xw4[q];
        amp[4 * q + 0] = (v.x * DTf) * DTf;
        amp[4 * q + 1] = (v.y * DTf) * DTf;
        amp[4 * q + 2] = (v.z * DTf) * DTf;
        amp[4 * q + 3] = (v.w * DTf) * DTf;
      }
    }

    if (ph > 0) {
      // R2-proven single-flag handshake: wF_nb >= ph certifies the neighbor
      // finished ALL of phase ph-1 (writeback drained AND reload done) ->
      // covers my data-dep (reload below) and anti-dep (my writeback).
      if (nb >= 0) {
        while (fload(wF + (size_t)nb * LSTRIDE) < (unsigned)ph)
          __builtin_amdgcn_s_sleep(1);
      }
      __syncthreads();                  // all waves wait for wave-0 poll
      const float2* rd = (ph & 1) ? g0 : g1;
      #pragma unroll
      for (int i = 0; i < WROWS; ++i) {
        const bool keep = wbT && (i >= KIN && i < KIN + SLAB);
        if (!keep && ((okBits >> i) & 1)) {
          const float2 f = gload2(rd + offBase + i * NX);
          if (i & 1) { a2[i >> 1].y = f.x; b2[i >> 1].y = f.y; }
          else       { a2[i >> 1].x = f.x; b2[i >> 1].x = f.y; }
        }
      }
      // per-register vmcnt waits inserted by compiler before first use
    }

    #pragma unroll
    for (int blk = 0; blk < KS / KIN; ++blk) {
      do_step(a2, b2, blk * KIN + 0, t0);
      do_step(b2, a2, blk * KIN + 1, t0);
      do_step(a2, b2, blk * KIN + 2, t0);
      do_step(b2, a2, blk * KIN + 3, t0);
      if (blk != KS / KIN - 1) exchange();
    }
    // after 16 steps: a2 = cur p(t0+15), b2 = prev p(t0+14); slab rows exact

    if (ph != NPHASE - 1) {
      float2* wr = (ph & 1) ? g1 : g0;
      if (wbT) {
        #pragma unroll
        for (int k = 0; k < SLAB; ++k) {
          const int i  = KIN + k;       // window rows 4..11 = my slab
          const int pr = 2 + (k >> 1);
          if (k & 1) gstore2(wr + offBase + i * NX, a2[pr].y, b2[pr].y);
          else       gstore2(wr + offBase + i * NX, a2[pr].x, b2[pr].x);
        }
      }
      __builtin_amdgcn_s_waitcnt(0);    // wb stores ack'd at LLC (per wave)
      __syncthreads();                  // whole WG drained
      if (tid == 0) fstore(wF + (size_t)bid * LSTRIDE, (unsigned)(ph + 1));
    }
  }
}

extern "C" void kernel_launch(void* const* d_in, const int* in_sizes, int n_in,
                              void* d_out, int out_size, void* d_ws, size_t ws_size,
                              hipStream_t stream) {
  const float* x     = (const float*)d_in[0];
  const float* vp    = (const float*)d_in[1];
  const int*   src_z = (const int*)d_in[2];
  const int*   src_x = (const int*)d_in[3];
  const int*   rec_z = (const int*)d_in[4];
  const int*   rec_x = (const int*)d_in[5];
  float* out = (float*)d_out;

  float* ws = (float*)d_ws;
  const size_t F = (size_t)NSHOTS * NZ * NX;
  float2* g0 = (float2*)ws;             // interleaved (cur,prev), 2F floats
  float2* g1 = (float2*)(ws + 2 * F);   // 2F floats
  unsigned* bar = (unsigned*)(ws + 4 * F);

  // zero the wFlag region (128B-strided)
  hipMemsetAsync(bar, 0, (size_t)NWG * LSTRIDE * sizeof(unsigned), stream);

  wave_pk<<<dim3(NWG), dim3(BLOCK), 0, stream>>>(
      g0, g1, vp, x, src_z, src_x, rec_z, rec_x, out, bar);
}

// Round 6
// 303.762 us; speedup vs baseline: 1.5165x; 1.5165x over previous
//
#include <hip/hip_runtime.h>

#define NSHOTS 4
#define NT     512
#define NZ     256
#define NX     256
#define NRECS  128

static constexpr float DTf    = 0.001f;
static constexpr float INVDH2 = 1.0f / (10.0f * 10.0f);

#define KSTEPS 16                 // fused steps per phase
#define TILE   32                 // interior tile edge
#define RPT    8                  // ext rows per thread (4 float2 pairs)
#define NPAIRS 4                  // RPT/2
#define NWAVES 8
#define BLOCK  512
#define NWG    (NSHOTS * 64)      // 256 WGs, one per CU (co-resident)
#define NPHASE (NT / KSTEPS)      // 32

typedef float v2f __attribute__((ext_vector_type(2)));
typedef unsigned long long ull;

// lane i <- lane i-1 (left x-neighbor); OOB lane 0 reads 0 (bound_ctrl=1)
__device__ __forceinline__ float nbr_left(float v) {
  return __int_as_float(__builtin_amdgcn_update_dpp(
      0, __float_as_int(v), 0x138 /*WAVE_SHR1*/, 0xf, 0xf, true));
}
// lane i <- lane i+1 (right x-neighbor); OOB lane 63 reads 0
__device__ __forceinline__ float nbr_right(float v) {
  return __int_as_float(__builtin_amdgcn_update_dpp(
      0, __float_as_int(v), 0x130 /*WAVE_SHL1*/, 0xf, 0xf, true));
}

// LLC-coherent (cross-XCD) 8B access: agent-scope relaxed -> sc0 sc1.
__device__ __forceinline__ ull pload(const ull* p) {
  return __hip_atomic_load(p, __ATOMIC_RELAXED, __HIP_MEMORY_SCOPE_AGENT);
}
__device__ __forceinline__ void pstore(ull* p, ull v) {
  __hip_atomic_store(p, v, __ATOMIC_RELAXED, __HIP_MEMORY_SCOPE_AGENT);
}

// pack (cur, prev) into one self-tagged 8B word: low 2 bits of prev's
// mantissa carry the phase tag (<= 3 ulp perturbation of halo prev only)
__device__ __forceinline__ ull pack_w(float cur, float prev, unsigned tg) {
  const unsigned hi = (__float_as_uint(prev) & ~3u) | tg;
  return ((ull)hi << 32) | (ull)__float_as_uint(cur);
}
__device__ __forceinline__ float w_cur(ull w) {
  return __uint_as_float((unsigned)w);
}
__device__ __forceinline__ float w_prev(ull w) {
  return __uint_as_float(((unsigned)(w >> 32)) & ~3u);
}
// per-buffer tag cycles 1,2,3 (phase q uses buffer q&1): never 0 (= memset)
__device__ __forceinline__ unsigned tag_of(int q) {
  return ((unsigned)(q >> 1) % 3u) + 1u;
}

__global__ __launch_bounds__(BLOCK, 4) void wave_pk(
    ull* __restrict__ gA, ull* __restrict__ gB,         // tagged (cur,prev) buffers
    const float* __restrict__ vp, const float* __restrict__ xwav,
    const int* __restrict__ src_z, const int* __restrict__ src_x,
    const int* __restrict__ rec_z, const int* __restrict__ rec_x,
    float* __restrict__ out)                            // [NSHOTS*NT*NRECS]
{
  const int bid  = blockIdx.x;
  const int s    = bid >> 6;
  const int tz   = (bid >> 3) & 7;
  const int tx   = bid & 7;
  const int tid  = threadIdx.x;
  const int w    = tid >> 6;
  const int lane = tid & 63;

  const int gz0 = tz * TILE - KSTEPS;
  const int gx0 = tx * TILE - KSTEPS;
  const int gx  = gx0 + lane;
  const int zb  = w * RPT;

  __shared__ float haloTop[2][NWAVES][64];
  __shared__ float haloBot[2][NWAVES][64];
  __shared__ float recTile[2][TILE][TILE + 1];
  __shared__ int   cntS;
  __shared__ int   lzA[NRECS], lxA[NRECS];
  __shared__ unsigned pkA[NRECS];

  // ---- prologue: receiver compaction + masks (as R2) ----
  if (tid == 0) cntS = 0;
  __syncthreads();
  if (tid < NRECS) {
    const int lz = rec_z[s * NRECS + tid] - tz * TILE;
    const int lx = rec_x[s * NRECS + tid] - tx * TILE;
    lzA[tid] = lz; lxA[tid] = lx;
    if ((unsigned)lz < (unsigned)TILE && (unsigned)lx < (unsigned)TILE) {
      const int k = atomicAdd(&cntS, 1);
      pkA[k] = (unsigned)tid | ((unsigned)lz << 8) | ((unsigned)lx << 16);
    }
  }
  __syncthreads();
  const int nRec = cntS;
  int myR = 0, myLz = 0, myLx = 0;
  if (tid < nRec) {
    const unsigned p = pkA[tid];
    myR = p & 255; myLz = (p >> 8) & 31; myLx = (p >> 16) & 31;
  }
  const bool wbRow = (w >= 2 && w < 6) && (lane >= KSTEPS && lane < KSTEPS + TILE);
  const int  ilz   = (w - 2) * RPT;
  const int  ilx   = lane - KSTEPS;
  unsigned recMask = 0;
  if (wbRow) {
    for (int r = 0; r < NRECS; ++r)
      if (lxA[r] == ilx && (unsigned)(lzA[r] - ilz) < (unsigned)RPT)
        recMask |= 1u << (lzA[r] - ilz);
  }

  // source mask, packed per row-pair
  const int slz = src_z[s] - gz0;
  const int slx = src_x[s] - gx0;
  const bool srcMine = (slx == lane) && ((unsigned)(slz - zb) < (unsigned)RPT);
  const int  srcI = slz - zb;
  v2f srcM2[NPAIRS];
  #pragma unroll
  for (int p = 0; p < NPAIRS; ++p) {
    srcM2[p].x = (srcMine && srcI == 2 * p)     ? 1.0f : 0.0f;
    srcM2[p].y = (srcMine && srcI == 2 * p + 1) ? 1.0f : 0.0f;
  }

  // phase-invariant per-row addresses/validity; c2 and d2=2-4c2 packed
  const bool xok = (unsigned)gx < (unsigned)NX;
  int   offRow[RPT];
  bool  okRow[RPT];
  v2f a2[NPAIRS], b2[NPAIRS], c22[NPAIRS], d22[NPAIRS];
  unsigned okMask = 0;
  #pragma unroll
  for (int p = 0; p < NPAIRS; ++p) {
    #pragma unroll
    for (int h = 0; h < 2; ++h) {
      const int i  = 2 * p + h;
      const int gz = gz0 + zb + i;
      const bool ok = xok && ((unsigned)gz < (unsigned)NZ);
      okRow[i]  = ok;
      if (ok) okMask |= 1u << i;
      offRow[i] = ok ? ((s * NZ + gz) * NX + gx) : 0;
      float v = ok ? vp[gz * NX + gx] : 0.0f;
      v *= DTf;
      const float c2 = v * v * INVDH2;
      if (h == 0) { c22[p].x = c2; d22[p].x = 2.0f - 4.0f * c2; }
      else        { c22[p].y = c2; d22[p].y = 2.0f - 4.0f * c2; }
    }
    a2[p] = (v2f)(0.0f); b2[p] = (v2f)(0.0f);
  }

  #pragma unroll 1
  for (int ph = 0; ph < NPHASE; ++ph) {
    const int t0 = ph * KSTEPS;

    // 16 source amps via 4 vector loads
    float amp[KSTEPS];
    {
      const float4* xw4 = (const float4*)(xwav + s * NT + t0);
      #pragma unroll
      for (int q = 0; q < KSTEPS / 4; ++q) {
        const float4 v = xw4[q];
        amp[4 * q + 0] = (v.x * DTf) * DTf;
        amp[4 * q + 1] = (v.y * DTf) * DTf;
        amp[4 * q + 2] = (v.z * DTf) * DTf;
        amp[4 * q + 3] = (v.w * DTf) * DTf;
      }
    }

    if (ph > 0 && !wbRow) {
      // fused poll+reload: spin on the tagged data words themselves.
      // tag match == producer (neighbor) finished phase ph-1 writeback AND
      // (by its program order + step barriers) its reloads of the buffer I
      // will overwrite this phase -> single mechanism covers data-dep and
      // anti-dep; no flags, no store drains, no broadcast barrier.
      const ull* gR = (ph & 1) ? gA : gB;   // buffer[(ph-1)&1]
      const unsigned tg = tag_of(ph - 1);
      ull vw[RPT];
      unsigned need = okMask;
      while (need) {
        ull t[RPT];
        #pragma unroll
        for (int i = 0; i < RPT; ++i)
          if (need & (1u << i)) t[i] = pload(gR + offRow[i]);
        #pragma unroll
        for (int i = 0; i < RPT; ++i)
          if ((need & (1u << i)) && (((unsigned)(t[i] >> 32)) & 3u) == tg) {
            vw[i] = t[i];
            need &= ~(1u << i);
          }
        if (need) __builtin_amdgcn_s_sleep(1);
      }
      #pragma unroll
      for (int i = 0; i < RPT; ++i) {
        const float cv = okRow[i] ? w_cur(vw[i])  : 0.0f;
        const float pv = okRow[i] ? w_prev(vw[i]) : 0.0f;
        if (i & 1) { a2[i >> 1].y = cv; b2[i >> 1].y = pv; }
        else       { a2[i >> 1].x = cv; b2[i >> 1].x = pv; }
      }
    }

    float recv[KSTEPS];

    // one step, row-pair packed: p' = d2*c + c2*sum - prev (+ src)
    auto do_step = [&](v2f (&cur)[NPAIRS], v2f (&nxt)[NPAIRS], int tau) {
      const int pb = tau & 1;
      haloTop[pb][w][lane] = cur[0].x;
      haloBot[pb][w][lane] = cur[NPAIRS - 1].y;
      __syncthreads();
      if (tau > 0 && tid < nRec) recv[tau - 1] = recTile[1 - pb][myLz][myLx];
      const float up0 = (w > 0)          ? haloBot[pb][w - 1][lane] : 0.0f;
      const float dn7 = (w < NWAVES - 1) ? haloTop[pb][w + 1][lane] : 0.0f;
      const v2f av = { amp[tau], amp[tau] };
      #pragma unroll
      for (int p = 0; p < NPAIRS; ++p) {
        const float cx = cur[p].x, cy = cur[p].y;
        const float upx = (p == 0)          ? up0 : cur[p - 1].y;
        const float dny = (p == NPAIRS - 1) ? dn7 : cur[p + 1].x;
        v2f ud, lr;
        ud.x = upx + cy;
        ud.y = cx + dny;
        lr.x = nbr_left(cx) + nbr_right(cx);
        lr.y = nbr_left(cy) + nbr_right(cy);
        const v2f sum = ud + lr;
        v2f t = __builtin_elementwise_fma(c22[p], sum, -nxt[p]);
        t = __builtin_elementwise_fma(d22[p], cur[p], t);
        t = __builtin_elementwise_fma(srcM2[p], av, t);
        nxt[p] = t;
      }
      if (recMask) {
        #pragma unroll
        for (int i = 0; i < RPT; ++i)
          if (recMask & (1u << i))
            recTile[pb][ilz + i][ilx] = (i & 1) ? nxt[i >> 1].y : nxt[i >> 1].x;
      }
    };

    #pragma unroll
    for (int h = 0; h < KSTEPS / 2; ++h) {
      do_step(a2, b2, 2 * h);
      do_step(b2, a2, 2 * h + 1);
    }

    if (ph != NPHASE - 1) {
      // interior writeback: tagged stores ARE the handshake signal.
      // No s_waitcnt(0), no flag store.
      ull* gW = (ph & 1) ? gB : gA;      // buffer[ph&1]
      const unsigned tgw = tag_of(ph);
      if (wbRow) {
        #pragma unroll
        for (int p = 0; p < NPAIRS; ++p) {
          pstore(gW + offRow[2 * p],     pack_w(a2[p].x, b2[p].x, tgw));
          pstore(gW + offRow[2 * p + 1], pack_w(a2[p].y, b2[p].y, tgw));
        }
      }
    }
    __syncthreads();                     // recTile[1] visible WG-wide

    // receiver flush (normal cached stores; read only after kernel end)
    if (tid < nRec) {
      recv[KSTEPS - 1] = recTile[1][myLz][myLx];
      #pragma unroll
      for (int t = 0; t < KSTEPS; ++t)
        out[(s * NT + (t0 + t)) * NRECS + myR] = recv[t];
    }
  }
}

extern "C" void kernel_launch(void* const* d_in, const int* in_sizes, int n_in,
                              void* d_out, int out_size, void* d_ws, size_t ws_size,
                              hipStream_t stream) {
  const float* x     = (const float*)d_in[0];
  const float* vp    = (const float*)d_in[1];
  const int*   src_z = (const int*)d_in[2];
  const int*   src_x = (const int*)d_in[3];
  const int*   rec_z = (const int*)d_in[4];
  const int*   rec_x = (const int*)d_in[5];
  float* out = (float*)d_out;

  const size_t F = (size_t)NSHOTS * NZ * NX;
  ull* gA = (ull*)d_ws;                 // tagged (cur,prev), F words
  ull* gB = gA + F;                     // F words

  // zero both buffers: tag bits 0 never match any valid tag (1..3)
  hipMemsetAsync(gA, 0, 2 * F * sizeof(ull), stream);

  wave_pk<<<dim3(NWG), dim3(BLOCK), 0, stream>>>(
      gA, gB, vp, x, src_z, src_x, rec_z, rec_x, out);
}